// Round 5
// baseline (1048.619 us; speedup 1.0000x reference)
//
#include <hip/hip_runtime.h>
#include <math.h>

#define NB 2
#define NT 1024
#define ND 1024
#define NH 8
#define NDK 128
#define NKEY 256
#define NBT (NB*NT)

// ---------------- RMSNorm: one block per row ----------------
__global__ __launch_bounds__(256) void rmsnorm_kernel(const float* __restrict__ x,
                                                      const float* __restrict__ w,
                                                      float* __restrict__ xn)
{
    int row = blockIdx.x, tid = threadIdx.x;
    const float* xr = x + (size_t)row * ND;
    float4 v = *(const float4*)(xr + tid * 4);
    float ss = v.x*v.x + v.y*v.y + v.z*v.z + v.w*v.w;
    #pragma unroll
    for (int d = 32; d > 0; d >>= 1) ss += __shfl_xor(ss, d);
    __shared__ float sred[4];
    int wv = tid >> 6, ln = tid & 63;
    if (ln == 0) sred[wv] = ss;
    __syncthreads();
    float tot = sred[0] + sred[1] + sred[2] + sred[3];
    float inv = 1.0f / sqrtf(tot * (1.0f / ND) + 1e-6f);
    float4 wt = *(const float4*)(w + tid * 4);
    float4 o;
    o.x = v.x * inv * wt.x; o.y = v.y * inv * wt.y;
    o.z = v.z * inv * wt.z; o.w = v.w * inv * wt.w;
    *(float4*)(xn + (size_t)row * ND + tid * 4) = o;
}

// ---------------- q GEMM, f64 accumulate: q[m,n] = sum_k xn[m,k]*w_q[n,k] ----
// M=2048 N=2048 K=1024. 128x64 tile, K-chunk 32, 256 threads, 8x4/thread.
#define TM 128
#define TN 64
#define TKC 32

__global__ __launch_bounds__(256) void gemm_nt_c64(const float* __restrict__ A,
                                                   const float* __restrict__ B,
                                                   double* __restrict__ C)
{
    const int lda = 1024, ldb = 1024, ldc = 2048;
    int n0 = blockIdx.x * TN;
    int m0 = blockIdx.y * TM;
    int tid = threadIdx.x;
    int tx = tid & 15, ty = tid >> 4;

    __shared__ float As[TKC][TM + 4];
    __shared__ float Bs[TKC][TN + 4];

    double acc[8][4];
    #pragma unroll
    for (int i = 0; i < 8; ++i)
        #pragma unroll
        for (int j = 0; j < 4; ++j) acc[i][j] = 0.0;

    for (int k0 = 0; k0 < 1024; k0 += TKC) {
        #pragma unroll
        for (int i = 0; i < 4; ++i) {
            int c = tid + i * 256;
            int r = c >> 3, kc = (c & 7) * 4;
            float4 v = *(const float4*)(A + (size_t)(m0 + r) * lda + k0 + kc);
            As[kc + 0][r] = v.x; As[kc + 1][r] = v.y;
            As[kc + 2][r] = v.z; As[kc + 3][r] = v.w;
        }
        #pragma unroll
        for (int i = 0; i < 2; ++i) {
            int c = tid + i * 256;
            int r = c >> 3, kc = (c & 7) * 4;
            float4 v = *(const float4*)(B + (size_t)(n0 + r) * ldb + k0 + kc);
            Bs[kc + 0][r] = v.x; Bs[kc + 1][r] = v.y;
            Bs[kc + 2][r] = v.z; Bs[kc + 3][r] = v.w;
        }
        __syncthreads();
        #pragma unroll
        for (int kk = 0; kk < TKC; ++kk) {
            double ad[8], bd[4];
            #pragma unroll
            for (int i = 0; i < 8; ++i) ad[i] = (double)As[kk][ty * 8 + i];
            #pragma unroll
            for (int j = 0; j < 4; ++j) bd[j] = (double)Bs[kk][tx * 4 + j];
            #pragma unroll
            for (int i = 0; i < 8; ++i)
                #pragma unroll
                for (int j = 0; j < 4; ++j)
                    acc[i][j] += ad[i] * bd[j];
        }
        __syncthreads();
    }
    #pragma unroll
    for (int i = 0; i < 8; ++i) {
        double* cp = C + (size_t)(m0 + ty * 8 + i) * ldc + n0 + tx * 4;
        double2 o0 = { acc[i][0], acc[i][1] };
        double2 o1 = { acc[i][2], acc[i][3] };
        *(double2*)(cp)     = o0;
        *(double2*)(cp + 2) = o1;
    }
}

// ---------------- sims GEMM: A=q(f64), B=keys(f32), C=sim(f64) --------------
// sim[z,t,k] = sum_dk q[t, z*128+dk] * keys[h,k,s,dk],  z = h*2+s
// per pass: 4 z-slices (zbase..zbase+3). M=2048, N=256, K=128.
__global__ __launch_bounds__(256) void gemm_a64_nt(const double* __restrict__ Q,
                                                   const float* __restrict__ keys,
                                                   double* __restrict__ simq,
                                                   int zbase)
{
    const int lda = 2048, ldb = 256, ldc = 256;
    int zloc = blockIdx.z;
    int z = zbase + zloc;
    const double* Ab = Q + (size_t)z * 128;
    const float*  Bb = keys + (size_t)(z >> 1) * 65536 + (size_t)(z & 1) * 128;
    double* Cb = simq + (size_t)zloc * 2048 * 256;

    int n0 = blockIdx.x * TN;
    int m0 = blockIdx.y * TM;
    int tid = threadIdx.x;
    int tx = tid & 15, ty = tid >> 4;

    __shared__ double As[TKC][TM + 2];
    __shared__ float  Bs[TKC][TN + 4];

    double acc[8][4];
    #pragma unroll
    for (int i = 0; i < 8; ++i)
        #pragma unroll
        for (int j = 0; j < 4; ++j) acc[i][j] = 0.0;

    for (int k0 = 0; k0 < 128; k0 += TKC) {
        // A tile: 128 rows x 32 doubles = 2048 double2 chunks / 256 thr = 8 ea
        #pragma unroll
        for (int i = 0; i < 8; ++i) {
            int c = tid + i * 256;
            int r = c >> 4, kc = (c & 15) * 2;
            double2 v = *(const double2*)(Ab + (size_t)(m0 + r) * lda + k0 + kc);
            As[kc + 0][r] = v.x; As[kc + 1][r] = v.y;
        }
        // B tile: 64 rows x 32 f32 = 512 float4 chunks / 256 thr = 2 ea
        #pragma unroll
        for (int i = 0; i < 2; ++i) {
            int c = tid + i * 256;
            int r = c >> 3, kc = (c & 7) * 4;
            float4 v = *(const float4*)(Bb + (size_t)(n0 + r) * ldb + k0 + kc);
            Bs[kc + 0][r] = v.x; Bs[kc + 1][r] = v.y;
            Bs[kc + 2][r] = v.z; Bs[kc + 3][r] = v.w;
        }
        __syncthreads();
        #pragma unroll
        for (int kk = 0; kk < TKC; ++kk) {
            double ad[8], bd[4];
            #pragma unroll
            for (int i = 0; i < 8; i += 2) {
                double2 v = *(const double2*)&As[kk][ty * 8 + i];
                ad[i] = v.x; ad[i + 1] = v.y;
            }
            #pragma unroll
            for (int j = 0; j < 4; ++j) bd[j] = (double)Bs[kk][tx * 4 + j];
            #pragma unroll
            for (int i = 0; i < 8; ++i)
                #pragma unroll
                for (int j = 0; j < 4; ++j)
                    acc[i][j] += ad[i] * bd[j];
        }
        __syncthreads();
    }
    #pragma unroll
    for (int i = 0; i < 8; ++i) {
        double* cp = Cb + (size_t)(m0 + ty * 8 + i) * ldc + n0 + tx * 4;
        double2 o0 = { acc[i][0], acc[i][1] };
        double2 o1 = { acc[i][2], acc[i][3] };
        *(double2*)(cp)     = o0;
        *(double2*)(cp + 2) = o1;
    }
}

// ---------------- Top-k on f64 sims: one wave per (bt, hloc) ----------------
__device__ inline double shflx_d(double v, int m)
{
    long long u = __double_as_longlong(v);
    int lo = (int)(u & 0xffffffffLL);
    int hi = (int)(u >> 32);
    lo = __shfl_xor(lo, m);
    hi = __shfl_xor(hi, m);
    return __longlong_as_double(((long long)hi << 32) | (unsigned int)lo);
}

__device__ inline void topk8d(double w[4], double* vs, int* is, int lane)
{
    #pragma unroll
    for (int r = 0; r < 8; ++r) {
        double bv = w[0]; int bi = lane;      // idx = c*64 + lane
        #pragma unroll
        for (int c = 1; c < 4; ++c) {
            double v = w[c]; int idx = c * 64 + lane;
            if (v > bv) { bv = v; bi = idx; }
        }
        #pragma unroll
        for (int d = 1; d < 64; d <<= 1) {
            double ov = shflx_d(bv, d);
            int    oi = __shfl_xor(bi, d);
            if (ov > bv || (ov == bv && oi < bi)) { bv = ov; bi = oi; }
        }
        vs[r] = bv; is[r] = bi;
        #pragma unroll
        for (int c = 0; c < 4; ++c)
            if (bi == c * 64 + lane) w[c] = -1.0e300;
    }
}

__global__ __launch_bounds__(64) void topk_kernel(const double* __restrict__ simq,
                                                  int* __restrict__ fi,
                                                  float* __restrict__ fw,
                                                  int zq)
{
    int g = blockIdx.x;                 // bt*2 + hloc
    int bt = g >> 1, hloc = g & 1;
    int h = zq * 2 + hloc;
    int lane = threadIdx.x;
    const double* s1p = simq + ((size_t)(hloc * 2 + 0) * NBT + bt) * NKEY;
    const double* s2p = simq + ((size_t)(hloc * 2 + 1) * NBT + bt) * NKEY;
    double w1[4], w2[4];
    #pragma unroll
    for (int c = 0; c < 4; ++c) {
        w1[c] = s1p[c * 64 + lane];
        w2[c] = s2p[c * 64 + lane];
    }
    double s1v[8], s2v[8]; int s1i[8], s2i[8];
    topk8d(w1, s1v, s1i, lane);
    topk8d(w2, s2v, s2i, lane);

    // 64 candidates: lane l -> (a = l>>3 from set1, b = l&7 from set2)
    double a = 0.0, b = 0.0;
    #pragma unroll
    for (int i = 0; i < 8; ++i) {
        a = ((lane >> 3) == i) ? s1v[i] : a;
        b = ((lane & 7) == i) ? s2v[i] : b;
    }
    double wv = a + b;
    double fsel = 0.0; int psel = 0;
    #pragma unroll
    for (int r = 0; r < 8; ++r) {
        double bv = wv; int bi = lane;
        #pragma unroll
        for (int d = 1; d < 64; d <<= 1) {
            double ov = shflx_d(bv, d);
            int    oi = __shfl_xor(bi, d);
            if (ov > bv || (ov == bv && oi < bi)) { bv = ov; bi = oi; }
        }
        if (lane == r) { fsel = bv; psel = bi; }
        if (lane == bi) wv = -1.0e300;
    }
    if (lane < 8) {
        int pa = psel >> 3, pb = psel & 7;
        int ii = 0, jj = 0;
        #pragma unroll
        for (int i = 0; i < 8; ++i) {
            ii = (pa == i) ? s1i[i] : ii;
            jj = (pb == i) ? s2i[i] : jj;
        }
        size_t og = (size_t)(bt * NH + h) * 8 + lane;
        fi[og] = ii * NKEY + jj;
        fw[og] = (float)fmax(fsel, 0.0);
    }
}

// ---------------- Expert gather + combine: one block per token ----------------
__global__ __launch_bounds__(256) void expert_kernel(const float* __restrict__ xn,
                                                     const int* __restrict__ fi,
                                                     const float* __restrict__ fw,
                                                     const float* __restrict__ down,
                                                     const float* __restrict__ up,
                                                     float* __restrict__ out)
{
    int bt = blockIdx.x;
    int tid = threadIdx.x;
    int wave = tid >> 6, lane = tid & 63;
    __shared__ float xs[ND];
    __shared__ float hs[64];
    __shared__ int   fis[64];
    __shared__ float fws[64];

    float4 xv = *(const float4*)(xn + (size_t)bt * ND + tid * 4);
    *(float4*)&xs[tid * 4] = xv;
    if (tid < 64) {
        fis[tid] = fi[(size_t)bt * 64 + tid];
        fws[tid] = fw[(size_t)bt * 64 + tid];
    }
    __syncthreads();

    for (int e0 = wave * 16; e0 < wave * 16 + 16; e0 += 2) {
        const float* dr0 = down + (size_t)fis[e0] * ND;
        const float* dr1 = down + (size_t)fis[e0 + 1] * ND;
        float s0 = 0.f, s1 = 0.f;
        #pragma unroll
        for (int c = 0; c < 4; ++c) {
            int idx = c * 256 + lane * 4;
            float4 d0 = *(const float4*)(dr0 + idx);
            float4 d1 = *(const float4*)(dr1 + idx);
            float4 xv2 = *(const float4*)&xs[idx];
            s0 += d0.x*xv2.x + d0.y*xv2.y + d0.z*xv2.z + d0.w*xv2.w;
            s1 += d1.x*xv2.x + d1.y*xv2.y + d1.z*xv2.z + d1.w*xv2.w;
        }
        #pragma unroll
        for (int d = 32; d > 0; d >>= 1) {
            s0 += __shfl_xor(s0, d);
            s1 += __shfl_xor(s1, d);
        }
        if (lane == 0) {
            float g0 = 0.5f * s0 * (1.0f + erff(s0 * 0.70710678118654752440f));
            float g1 = 0.5f * s1 * (1.0f + erff(s1 * 0.70710678118654752440f));
            hs[e0]     = g0 * fws[e0];
            hs[e0 + 1] = g1 * fws[e0 + 1];
        }
    }
    __syncthreads();

    float4 acc = { 0.f, 0.f, 0.f, 0.f };
    for (int e = 0; e < 64; e += 4) {
        const float* u0 = up + (size_t)fis[e + 0] * ND + tid * 4;
        const float* u1 = up + (size_t)fis[e + 1] * ND + tid * 4;
        const float* u2 = up + (size_t)fis[e + 2] * ND + tid * 4;
        const float* u3 = up + (size_t)fis[e + 3] * ND + tid * 4;
        float4 v0 = *(const float4*)u0;
        float4 v1 = *(const float4*)u1;
        float4 v2 = *(const float4*)u2;
        float4 v3 = *(const float4*)u3;
        float h0 = hs[e + 0], h1 = hs[e + 1], h2 = hs[e + 2], h3 = hs[e + 3];
        acc.x += h0*v0.x + h1*v1.x + h2*v2.x + h3*v3.x;
        acc.y += h0*v0.y + h1*v1.y + h2*v2.y + h3*v3.y;
        acc.z += h0*v0.z + h1*v1.z + h2*v2.z + h3*v3.z;
        acc.w += h0*v0.w + h1*v1.w + h2*v2.w + h3*v3.w;
    }
    *(float4*)(out + (size_t)bt * ND + tid * 4) = acc;
}

extern "C" void kernel_launch(void* const* d_in, const int* in_sizes, int n_in,
                              void* d_out, int out_size, void* d_ws, size_t ws_size,
                              hipStream_t stream)
{
    (void)in_sizes; (void)n_in; (void)out_size; (void)ws_size;
    const float* x      = (const float*)d_in[0];
    const float* w_q    = (const float*)d_in[1];
    const float* keys   = (const float*)d_in[2];
    const float* down   = (const float*)d_in[3];
    const float* up     = (const float*)d_in[4];
    const float* norm_w = (const float*)d_in[5];
    float* out = (float*)d_out;

    // ws layout (57 MB high-water, same as previously-executed budget):
    //   [0, 8MB)    xn    f32 2048x1024
    //   [8, 40MB)   q     f64 2048x2048
    //   [40, 56MB)  simq  f64 4 x 2048 x 256   (reused across 4 passes)
    //   [56MB, ..)  fi (512KB) + fw (512KB)
    char* wsb = (char*)d_ws;
    float*  xn   = (float*)wsb;
    double* q    = (double*)(wsb + ((size_t)8 << 20));
    double* simq = (double*)(wsb + ((size_t)40 << 20));
    int*    fi   = (int*)(wsb + ((size_t)56 << 20));
    float*  fw   = (float*)(wsb + ((size_t)56 << 20) + 131072 * 4);

    rmsnorm_kernel<<<NBT, 256, 0, stream>>>(x, norm_w, xn);

    gemm_nt_c64<<<dim3(2048 / TN, 2048 / TM, 1), 256, 0, stream>>>(xn, w_q, q);

    for (int zq = 0; zq < 4; ++zq) {
        gemm_a64_nt<<<dim3(NKEY / TN, 2048 / TM, 4), 256, 0, stream>>>(
            q, keys, simq, zq * 4);
        topk_kernel<<<NBT * 2, 64, 0, stream>>>(simq, fi, fw, zq);
    }

    expert_kernel<<<NBT, 256, 0, stream>>>(xn, fi, fw, down, up, out);
}